// Round 11
// baseline (1088.550 us; speedup 1.0000x reference)
//
#include <hip/hip_runtime.h>
#include <hip/hip_bf16.h>
#include <stdint.h>

#define L_SEQ 2048
#define DMODEL 768
#define DI_ 1536
#define E2_ 3072
#define NLAYER 2
#define SSTATE 16
#define DBCN 80
#define KPAD 64
#define VOCAB 32000
#define NCHUNK 32
#define TCH 64

typedef __bf16 bf16x8 __attribute__((ext_vector_type(8)));
typedef float f32x4 __attribute__((ext_vector_type(4)));

__device__ __forceinline__ unsigned short f2bf(float x) {
  union { float f; uint32_t u; } v; v.f = x;
  uint32_t r = (v.u + 0x7FFFu + ((v.u >> 16) & 1u)) >> 16;
  return (unsigned short)r;
}
__device__ __forceinline__ float bf2f(unsigned short x) {
  union { uint32_t u; float f; } v; v.u = (uint32_t)x << 16; return v.f;
}
__device__ __forceinline__ float siluf_(float x) { return x / (1.f + __expf(-x)); }
__device__ __forceinline__ float softplusf_(float x) {
  return fmaxf(x, 0.f) + log1pf(__expf(-fabsf(x)));
}

// ---------------- weight conversion (vectorized x4) ----------------
__global__ __launch_bounds__(256) void cvt2_kernel(const float* __restrict__ f,
                                                   const float* __restrict__ b,
                                                   unsigned short* __restrict__ dst, long n) {
  long i = ((long)blockIdx.x * 256 + threadIdx.x) * 4;
  if (i >= n) return;
  const float* s = blockIdx.z ? b : f;
  float4 v = *(const float4*)(s + i);
  ushort4 o; o.x = f2bf(v.x); o.y = f2bf(v.y); o.z = f2bf(v.z); o.w = f2bf(v.w);
  *(ushort4*)(dst + (long)blockIdx.z * n + i) = o;
}
__global__ __launch_bounds__(256) void cvt1_kernel(const float* __restrict__ s,
                                                   unsigned short* __restrict__ dst, long n) {
  long i = ((long)blockIdx.x * 256 + threadIdx.x) * 4;
  if (i >= n) return;
  float4 v = *(const float4*)(s + i);
  ushort4 o; o.x = f2bf(v.x); o.y = f2bf(v.y); o.z = f2bf(v.z); o.w = f2bf(v.w);
  *(ushort4*)(dst + i) = o;
}
// dt_w (NLAYER*DI_ rows x 48) -> padded (x64)
__global__ __launch_bounds__(256) void cvtdtw_kernel(const float* __restrict__ f,
                                                     const float* __restrict__ b,
                                                     unsigned short* __restrict__ dst) {
  long n = (long)NLAYER * DI_ * KPAD;
  long i = (long)blockIdx.x * 256 + threadIdx.x;
  if (i >= n) return;
  long r = i >> 6; int c = (int)(i & 63);
  const float* s = blockIdx.z ? b : f;
  dst[(long)blockIdx.z * n + i] = f2bf(c < 48 ? s[r * 48 + c] : 0.f);
}

// ---------------- embedding gather (+flip for dir=1), float4 ----------------
__global__ __launch_bounds__(256) void gather_kernel(const int* __restrict__ ids,
                                                     const float* __restrict__ emb,
                                                     float* __restrict__ res) {
  int idx = blockIdx.x * 256 + threadIdx.x;           // over L*D/4
  int z = blockIdx.z;
  int l = idx / (DMODEL / 4), c = idx % (DMODEL / 4);
  int srcl = z ? (L_SEQ - 1 - l) : l;
  float4 v = *(const float4*)(emb + (size_t)ids[srcl] * DMODEL + c * 4);
  *(float4*)(res + (size_t)z * L_SEQ * DMODEL + (size_t)l * DMODEL + c * 4) = v;
}

// ---------------- residual add + rmsnorm -> bf16 ----------------
__global__ __launch_bounds__(256) void addnorm_kernel(float* __restrict__ res,
                                                      const float* __restrict__ hid,
                                                      const float* __restrict__ wf,
                                                      const float* __restrict__ wb, int woff,
                                                      unsigned short* __restrict__ out) {
  int z = blockIdx.z, l = blockIdx.x, t = threadIdx.x;
  const float* w = (z ? wb : wf) + woff;
  size_t base = ((size_t)z * L_SEQ + l) * DMODEL;
  float v[3]; float ss = 0.f;
  #pragma unroll
  for (int i = 0; i < 3; ++i) {
    int c = t + i * 256;
    float x = res[base + c];
    if (hid) { x += hid[base + c]; res[base + c] = x; }
    v[i] = x; ss += x * x;
  }
  #pragma unroll
  for (int m = 32; m; m >>= 1) ss += __shfl_xor(ss, m);
  __shared__ float red[4];
  if ((t & 63) == 0) red[t >> 6] = ss;
  __syncthreads();
  ss = red[0] + red[1] + red[2] + red[3];
  float inv = rsqrtf(ss * (1.f / DMODEL) + 1e-5f);
  #pragma unroll
  for (int i = 0; i < 3; ++i) {
    int c = t + i * 256;
    out[base + c] = f2bf(v[i] * inv * w[c]);
  }
}

// final rmsnorm(hid+res) -> bf16 into hcat with flip+col-offset for dir=1
__global__ __launch_bounds__(256) void finalcat_kernel(const float* __restrict__ res,
                                                       const float* __restrict__ hid,
                                                       const float* __restrict__ wf,
                                                       const float* __restrict__ wb,
                                                       unsigned short* __restrict__ hcat) {
  int z = blockIdx.z, l = blockIdx.x, t = threadIdx.x;
  const float* w = z ? wb : wf;
  size_t base = ((size_t)z * L_SEQ + l) * DMODEL;
  float v[3]; float ss = 0.f;
  #pragma unroll
  for (int i = 0; i < 3; ++i) {
    int c = t + i * 256;
    float x = res[base + c] + hid[base + c];
    v[i] = x; ss += x * x;
  }
  #pragma unroll
  for (int m = 32; m; m >>= 1) ss += __shfl_xor(ss, m);
  __shared__ float red[4];
  if ((t & 63) == 0) red[t >> 6] = ss;
  __syncthreads();
  ss = red[0] + red[1] + red[2] + red[3];
  float inv = rsqrtf(ss * (1.f / DMODEL) + 1e-5f);
  int outl = z ? (L_SEQ - 1 - l) : l;
  #pragma unroll
  for (int i = 0; i < 3; ++i) {
    int c = t + i * 256;
    hcat[(size_t)outl * DI_ + z * DMODEL + c] = f2bf(v[i] * inv * w[c]);
  }
}

// ---------------- circular depthwise conv K=4 + silu (bf16 in/out) ----------------
__global__ __launch_bounds__(256) void conv_kernel(const unsigned short* __restrict__ xzb,
                                                   const float* __restrict__ cwf,
                                                   const float* __restrict__ cwb,
                                                   const float* __restrict__ cbf,
                                                   const float* __restrict__ cbb, int layer,
                                                   unsigned short* __restrict__ xbf) {
  int z = blockIdx.z;
  int idx = blockIdx.x * 256 + threadIdx.x;           // over L*DI
  int l = idx / DI_, d = idx % DI_;
  const float* cw = (z ? cwb : cwf) + layer * DI_ * 4;
  const float* cb = (z ? cbb : cbf) + layer * DI_;
  const unsigned short* xzp = xzb + (size_t)z * L_SEQ * E2_;
  float acc = cb[d];
  #pragma unroll
  for (int k = 0; k < 4; ++k) {
    int ls = (l + k - 3 + L_SEQ) & (L_SEQ - 1);
    acc += cw[d * 4 + k] * bf2f(xzp[(size_t)ls * E2_ + d]);
  }
  xbf[(size_t)z * L_SEQ * DI_ + idx] = f2bf(siluf_(acc));
}

// ---------------- chunk-parallel selective scan ----------------
__global__ __launch_bounds__(256) void scanA_kernel(const unsigned short* __restrict__ delta,
                                                    const unsigned short* __restrict__ u,
                                                    const float* __restrict__ dbc,
                                                    const float* __restrict__ Af,
                                                    const float* __restrict__ Ab, int aoff,
                                                    float* __restrict__ Pg,
                                                    float* __restrict__ Qg) {
  const int z = blockIdx.z;
  const int d0 = blockIdx.x * 16;
  const int c = blockIdx.y;
  const int tid = threadIdx.x;
  const int s = tid & 15;
  const int g = tid >> 4;
  const int d = d0 + g;
  __shared__ float sd[16 * 65], su2[16 * 65], sb2[16 * 65];
  const size_t zo = (size_t)z * L_SEQ * DI_;
  const unsigned short* dl = delta + zo;
  const unsigned short* ul = u + zo;
  const float* bc = dbc + (size_t)z * L_SEQ * DBCN;
  const float A = -__expf(((z ? Ab : Af) + aoff)[d * SSTATE + s]);
  const int l0 = c * TCH;
  #pragma unroll
  for (int i = 0; i < 4; ++i) {
    int idx = tid + i * 256;
    int di = idx & 15, li = idx >> 4;
    size_t gl = (size_t)(l0 + li);
    sd[di * 65 + li]  = bf2f(dl[gl * DI_ + d0 + di]);
    su2[di * 65 + li] = bf2f(ul[gl * DI_ + d0 + di]);
    sb2[di * 65 + li] = bc[gl * DBCN + 48 + di];
  }
  __syncthreads();
  float h = 0.f, sda = 0.f;
  #pragma unroll 4
  for (int t = 0; t < TCH; ++t) {
    float dlt = sd[g * 65 + t];
    float uu  = su2[g * 65 + t];
    float bb  = sb2[s * 65 + t];
    float a = __expf(dlt * A);
    h = a * h + dlt * uu * bb;
    sda += dlt;
  }
  size_t o = ((size_t)(z * NCHUNK + c) * DI_ + d) * SSTATE + s;
  Pg[o] = __expf(sda * A);
  Qg[o] = h;
}

__global__ __launch_bounds__(256) void scanB_kernel(const float* __restrict__ Pg,
                                                    const float* __restrict__ Qg,
                                                    float* __restrict__ hin) {
  int idx = blockIdx.x * 256 + threadIdx.x;   // over 2*DI*16
  int z = idx / (DI_ * SSTATE);
  int r = idx % (DI_ * SSTATE);
  float h = 0.f;
  #pragma unroll
  for (int c = 0; c < NCHUNK; ++c) {
    size_t o = (size_t)(z * NCHUNK + c) * DI_ * SSTATE + r;
    hin[o] = h;
    h = Pg[o] * h + Qg[o];
  }
}

__global__ __launch_bounds__(256) void scanC_kernel(const unsigned short* __restrict__ delta,
                                                    const unsigned short* __restrict__ u,
                                                    const float* __restrict__ dbc,
                                                    const unsigned short* __restrict__ xzb,
                                                    const float* __restrict__ Af,
                                                    const float* __restrict__ Ab, int aoff,
                                                    const float* __restrict__ Dpf,
                                                    const float* __restrict__ Dpb, int doff,
                                                    const float* __restrict__ hin,
                                                    unsigned short* __restrict__ yb) {
  const int z = blockIdx.z;
  const int d0 = blockIdx.x * 16;
  const int c = blockIdx.y;
  const int tid = threadIdx.x;
  const int s = tid & 15;
  const int g = tid >> 4;
  const int d = d0 + g;
  __shared__ float sd[16 * 65], su2[16 * 65], sb2[16 * 65], sc2[16 * 65], sy2[16 * 65];
  const size_t zo = (size_t)z * L_SEQ * DI_;
  const unsigned short* dl = delta + zo;
  const unsigned short* ul = u + zo;
  const float* bc = dbc + (size_t)z * L_SEQ * DBCN;
  const float A = -__expf(((z ? Ab : Af) + aoff)[d * SSTATE + s]);
  const int l0 = c * TCH;
  #pragma unroll
  for (int i = 0; i < 4; ++i) {
    int idx = tid + i * 256;
    int di = idx & 15, li = idx >> 4;
    size_t gl = (size_t)(l0 + li);
    sd[di * 65 + li]  = bf2f(dl[gl * DI_ + d0 + di]);
    su2[di * 65 + li] = bf2f(ul[gl * DI_ + d0 + di]);
    sb2[di * 65 + li] = bc[gl * DBCN + 48 + di];
    sc2[di * 65 + li] = bc[gl * DBCN + 64 + di];
  }
  __syncthreads();
  float h = hin[((size_t)(z * NCHUNK + c) * DI_ + d) * SSTATE + s];
  for (int t = 0; t < TCH; t += 2) {
    float dlt0 = sd[g * 65 + t],     uu0 = su2[g * 65 + t];
    float bb0  = sb2[s * 65 + t],    cc0 = sc2[s * 65 + t];
    float dlt1 = sd[g * 65 + t + 1], uu1 = su2[g * 65 + t + 1];
    float bb1  = sb2[s * 65 + t + 1], cc1 = sc2[s * 65 + t + 1];
    float a0 = __expf(dlt0 * A); h = a0 * h + dlt0 * uu0 * bb0; float p0 = h * cc0;
    float a1 = __expf(dlt1 * A); h = a1 * h + dlt1 * uu1 * bb1; float p1 = h * cc1;
    p0 += __shfl_xor(p0, 1); p1 += __shfl_xor(p1, 1);
    p0 += __shfl_xor(p0, 2); p1 += __shfl_xor(p1, 2);
    p0 += __shfl_xor(p0, 4); p1 += __shfl_xor(p1, 4);
    p0 += __shfl_xor(p0, 8); p1 += __shfl_xor(p1, 8);
    if (s == 0) { sy2[g * 65 + t] = p0; sy2[g * 65 + t + 1] = p1; }
  }
  __syncthreads();
  const float* Dp = (z ? Dpb : Dpf) + doff;
  #pragma unroll
  for (int i = 0; i < 4; ++i) {
    int idx = tid + i * 256;
    int di = idx & 15, li = idx >> 4;
    int l = l0 + li;
    float y = sy2[di * 65 + li];
    float uu = su2[di * 65 + li];
    float zz = bf2f(xzb[(size_t)z * L_SEQ * E2_ + (size_t)l * E2_ + DI_ + d0 + di]);
    float v = (y + Dp[d0 + di] * uu) * siluf_(zz);
    yb[zo + (size_t)l * DI_ + d0 + di] = f2bf(v);
  }
}

// ---------------- 128^2 bf16 MFMA GEMM (2-phase dbuf) ----------------
// EPI: 0 = f32, 1 = softplus(v+bias[col]) -> bf16, 2 = bf16, 3 = f32(N) + bf16(KPAD)
template <int EPI>
__global__ __launch_bounds__(256)
void gemm_bt(const unsigned short* __restrict__ Ag, long sAz,
             const unsigned short* __restrict__ Bg, long sBz,
             float* __restrict__ Cf, unsigned short* __restrict__ Cb,
             long sCz, long sCbz,
             int M, int N, int K,
             const float* __restrict__ bias, long sBiasz) {
  __shared__ __align__(16) unsigned short sA[2][128 * 64];
  __shared__ __align__(16) unsigned short sB[2][128 * 64];
  const int tid = threadIdx.x;
  const int lane = tid & 63;
  const int wv = tid >> 6;
  const int z = blockIdx.z;

  const int nbx = gridDim.x, nby = gridDim.y;
  const int nwg = nbx * nby;
  int hwid = blockIdx.y * nbx + blockIdx.x;
  int q = nwg >> 3, r = nwg & 7;
  int xcd = hwid & 7, slot = hwid >> 3;
  int sbid = (xcd < r ? xcd * (q + 1) : r * (q + 1) + (xcd - r) * q) + slot;
  const int NG = 16;
  int full = nbx / NG;
  int fullBlocks = full * NG * nby;
  int g, na, rem;
  if (sbid < fullBlocks) { g = sbid / (NG * nby); rem = sbid - g * (NG * nby); na = NG; }
  else { g = full; rem = sbid - fullBlocks; na = nbx - full * NG; }
  int ni = rem % na;
  int mi = rem / na;
  const int n0 = (g * NG + ni) * 128;
  const int m0 = mi * 128;

  const unsigned short* A = Ag + (size_t)z * sAz;
  const unsigned short* B = Bg + (size_t)z * sBz;
  const int wm = (wv >> 1) * 64;
  const int wn = (wv & 1) * 64;
  const int lr = lane & 15;
  const int lq = lane >> 4;

  f32x4 acc[4][4] = {};

  int prow[4], pcsw[4];
  #pragma unroll
  for (int i = 0; i < 4; ++i) {
    int p = (i * 4 + wv) * 64 + lane;
    int row = p >> 3, sl = p & 7;
    prow[i] = row;
    pcsw[i] = (sl ^ (row & 7)) * 8;
  }

  auto stage = [&](int b, int k0) {
    #pragma unroll
    for (int i = 0; i < 4; ++i) {
      int row = prow[i];
      int ra = m0 + row; if (ra > M - 1) ra = M - 1;
      int rb = n0 + row; if (rb > N - 1) rb = N - 1;
      const unsigned short* ga = A + (size_t)ra * K + k0 + pcsw[i];
      const unsigned short* gb = B + (size_t)rb * K + k0 + pcsw[i];
      __builtin_amdgcn_global_load_lds(
          (const __attribute__((address_space(1))) unsigned int*)ga,
          (__attribute__((address_space(3))) unsigned int*)(sA[b] + (i * 4 + wv) * 512),
          16, 0, 0);
      __builtin_amdgcn_global_load_lds(
          (const __attribute__((address_space(1))) unsigned int*)gb,
          (__attribute__((address_space(3))) unsigned int*)(sB[b] + (i * 4 + wv) * 512),
          16, 0, 0);
    }
  };

  const int nt = K >> 6;
  stage(0, 0);
  __syncthreads();
  int cur = 0;
  for (int t = 0; t < nt; ++t) {
    if (t + 1 < nt) stage(cur ^ 1, (t + 1) << 6);
    #pragma unroll
    for (int kk = 0; kk < 64; kk += 32) {
      bf16x8 af[4], bfr[4];
      const int ks = (kk >> 3) + lq;
      #pragma unroll
      for (int i = 0; i < 4; ++i) {
        int rra = wm + i * 16 + lr;
        int rrb = wn + i * 16 + lr;
        af[i]  = *(const bf16x8*)(sA[cur] + rra * 64 + ((ks ^ (rra & 7)) << 3));
        bfr[i] = *(const bf16x8*)(sB[cur] + rrb * 64 + ((ks ^ (rrb & 7)) << 3));
      }
      #pragma unroll
      for (int mi2 = 0; mi2 < 4; ++mi2)
        #pragma unroll
        for (int ni2 = 0; ni2 < 4; ++ni2)
          acc[mi2][ni2] = __builtin_amdgcn_mfma_f32_16x16x32_bf16(af[mi2], bfr[ni2], acc[mi2][ni2], 0, 0, 0);
    }
    __syncthreads();
    cur ^= 1;
  }

  const int orow0 = m0 + wm + lq * 4;
  const int ocol0 = n0 + wn + lr;
  #pragma unroll
  for (int mi2 = 0; mi2 < 4; ++mi2) {
    #pragma unroll
    for (int ni2 = 0; ni2 < 4; ++ni2) {
      int col = ocol0 + ni2 * 16;
      #pragma unroll
      for (int j = 0; j < 4; ++j) {
        int row = orow0 + mi2 * 16 + j;
        if (row >= M) continue;
        float v = acc[mi2][ni2][j];
        if constexpr (EPI == 3) {
          if (col < N) Cf[(size_t)z * sCz + (size_t)row * N + col] = v;
          if (col < KPAD) Cb[(size_t)z * sCbz + (size_t)row * KPAD + col] = f2bf(v);
        } else {
          if (col >= N) continue;
          if constexpr (EPI == 1) {
            Cb[(size_t)z * sCz + (size_t)row * N + col] =
                f2bf(softplusf_(v + bias[(size_t)z * sBiasz + col]));
          } else if constexpr (EPI == 2) {
            Cb[(size_t)z * sCz + (size_t)row * N + col] = f2bf(v);
          } else {
            Cf[(size_t)z * sCz + (size_t)row * N + col] = v;
          }
        }
      }
    }
  }
}

// ---------------- 256^2 bf16 MFMA GEMM, 8 waves, 4-phase counted-vmcnt pipeline ----
// Per K-tile: 4 phases, each {stage 1 half-tile of tile t+1 (2 gload_lds);
// [q0 only: vmcnt(2)+barrier = all tile-t halves landed, newest stage stays in
// flight]; ds_read quadrant frags; setprio(1); 16 MFMA; setprio(0); barrier}.
// Quadrants = (kk, ni-half): A-frags read once per kk, reused for both ni-halves.
__global__ __launch_bounds__(512, 2)
void gemm_bt256(const unsigned short* __restrict__ A,
                const unsigned short* __restrict__ B,
                float* __restrict__ Cf, int M, int N, int K) {
  __shared__ __align__(16) unsigned short sA[2][256 * 64];
  __shared__ __align__(16) unsigned short sB[2][256 * 64];
  const int tid = threadIdx.x;
  const int lane = tid & 63;
  const int wv = tid >> 6;            // 0..7

  const int nbx = gridDim.x, nby = gridDim.y;
  const int nwg = nbx * nby;
  int hwid = blockIdx.y * nbx + blockIdx.x;
  int q = nwg >> 3, r = nwg & 7;
  int xcd = hwid & 7, slot = hwid >> 3;
  int sbid = (xcd < r ? xcd * (q + 1) : r * (q + 1) + (xcd - r) * q) + slot;
  const int NG = 8;
  int full = nbx / NG;
  int fullBlocks = full * NG * nby;
  int g, na, rem;
  if (sbid < fullBlocks) { g = sbid / (NG * nby); rem = sbid - g * (NG * nby); na = NG; }
  else { g = full; rem = sbid - fullBlocks; na = nbx - full * NG; }
  int ni = rem % na;
  int mi = rem / na;
  const int n0 = (g * NG + ni) * 256;
  const int m0 = mi * 256;

  const int wm = (wv >> 2) * 128;     // 2 waves in M
  const int wn = (wv & 3) * 64;       // 4 waves in N
  const int lr = lane & 15;
  const int lq = lane >> 4;

  f32x4 acc[8][4] = {};

  // stage one half-tile (128 rows x 64 cols) of operand: 2 x 16B per thread
  auto stage_half = [&](int b, int k0, int h, bool isA) {
    const unsigned short* Op = isA ? A : B;
    const int o0 = isA ? m0 : n0;
    const int lim = (isA ? M : N) - 1;
    unsigned short* sOp = isA ? sA[b] : sB[b];
    #pragma unroll
    for (int j = 0; j < 2; ++j) {
      int p = h * 1024 + (j * 8 + wv) * 64 + lane;
      int row = p >> 3, sl = (p & 7) ^ (row & 7);
      int rr = o0 + row; if (rr > lim) rr = lim;
      __builtin_amdgcn_global_load_lds(
          (const __attribute__((address_space(1))) unsigned int*)(Op + (size_t)rr * K + k0 + sl * 8),
          (__attribute__((address_space(3))) unsigned int*)(sOp + (size_t)(h * 1024 + (j * 8 + wv) * 64) * 8),
          16, 0, 0);
    }
  };

#define READ_A(kk_) { const int ks = ((kk_) >> 3) + lq;                              \
    _Pragma("unroll") for (int i = 0; i < 8; ++i) {                                  \
      int rra = wm + i * 16 + lr;                                                    \
      af[i] = *(const bf16x8*)(sA[cur] + rra * 64 + ((ks ^ (rra & 7)) << 3)); } }
#define READ_B(kk_, nh_) { const int ks = ((kk_) >> 3) + lq;                         \
    _Pragma("unroll") for (int i = 0; i < 2; ++i) {                                  \
      int rrb = wn + ((nh_) * 2 + i) * 16 + lr;                                      \
      bfr[i] = *(const bf16x8*)(sB[cur] + rrb * 64 + ((ks ^ (rrb & 7)) << 3)); } }
#define MFMA16(nh_) { __builtin_amdgcn_s_setprio(1);                                 \
    _Pragma("unroll") for (int mi2 = 0; mi2 < 8; ++mi2) {                            \
      acc[mi2][(nh_)*2]   = __builtin_amdgcn_mfma_f32_16x16x32_bf16(af[mi2], bfr[0], acc[mi2][(nh_)*2],   0, 0, 0); \
      acc[mi2][(nh_)*2+1] = __builtin_amdgcn_mfma_f32_16x16x32_bf16(af[mi2], bfr[1], acc[mi2][(nh_)*2+1], 0, 0, 0); } \
    __builtin_amdgcn_s_setprio(0); }
#define BARRIER() __builtin_amdgcn_s_barrier()

  const int nt = K >> 6;
  // prologue: all 4 halves of tile 0
  stage_half(0, 0, 0, true);  stage_half(0, 0, 1, true);
  stage_half(0, 0, 0, false); stage_half(0, 0, 1, false);
  int cur = 0;
  for (int t = 0; t < nt; ++t) {
    const int k1 = (t + 1) << 6;
    const bool more = (t + 1 < nt);
    bf16x8 af[8], bfr[2];
    // ---- phase 0: (kk=0, nh=0), stage A-half0 of t+1 ----
    if (more) {
      stage_half(cur ^ 1, k1, 0, true);
      asm volatile("s_waitcnt vmcnt(2)" ::: "memory");  // tile-t halves landed; newest stays in flight
    } else {
      asm volatile("s_waitcnt vmcnt(0)" ::: "memory");
    }
    BARRIER();
    READ_A(0); READ_B(0, 0); MFMA16(0);
    BARRIER();
    // ---- phase 1: (kk=0, nh=1), stage A-half1 ----
    if (more) stage_half(cur ^ 1, k1, 1, true);
    READ_B(0, 1); MFMA16(1);
    BARRIER();
    // ---- phase 2: (kk=32, nh=0), stage B-half0 ----
    if (more) stage_half(cur ^ 1, k1, 0, false);
    READ_A(32); READ_B(32, 0); MFMA16(0);
    BARRIER();
    // ---- phase 3: (kk=32, nh=1), stage B-half1 ----
    if (more) stage_half(cur ^ 1, k1, 1, false);
    READ_B(32, 1); MFMA16(1);
    BARRIER();   // WAR guard: all reads of buf[cur] done before t+1 stages into it
    cur ^= 1;
  }
#undef READ_A
#undef READ_B
#undef MFMA16
#undef BARRIER

  const int orow0 = m0 + wm + lq * 4;
  const int ocol0 = n0 + wn + lr;
  #pragma unroll
  for (int mi2 = 0; mi2 < 8; ++mi2) {
    #pragma unroll
    for (int ni2 = 0; ni2 < 4; ++ni2) {
      int col = ocol0 + ni2 * 16;
      if (col >= N) continue;
      #pragma unroll
      for (int j = 0; j < 4; ++j) {
        int row = orow0 + mi2 * 16 + j;
        if (row >= M) continue;
        Cf[(size_t)row * N + col] = acc[mi2][ni2][j];
      }
    }
  }
}

// ==================== host launcher ====================
extern "C" void kernel_launch(void* const* d_in, const int* in_sizes, int n_in,
                              void* d_out, int out_size, void* d_ws, size_t ws_size,
                              hipStream_t stream) {
  const int* ids = (const int*)d_in[0];
  const float* embedding = (const float*)d_in[1];
  const float* lm_head = (const float*)d_in[2];
  const float* F[11]; const float* Bp[11];
  for (int i = 0; i < 11; ++i) { F[i] = (const float*)d_in[3 + i]; Bp[i] = (const float*)d_in[14 + i]; }

  char* ws = (char*)d_ws;
  size_t off = 0;
  auto AL = [&](size_t bytes) { size_t o = off; off += (bytes + 255) & ~(size_t)255; return o; };
  size_t o_win  = AL((size_t)2 * NLAYER * E2_ * DMODEL * 2);
  size_t o_wxp  = AL((size_t)2 * NLAYER * DBCN * DI_ * 2);
  size_t o_wdtw = AL((size_t)2 * NLAYER * DI_ * KPAD * 2);
  size_t o_wout = AL((size_t)2 * NLAYER * DMODEL * DI_ * 2);
  size_t o_wlm  = AL((size_t)DMODEL * DI_ * 2);
  size_t o_wemb = AL((size_t)VOCAB * DMODEL * 2);
  size_t o_dtb  = AL((size_t)2 * NLAYER * DI_ * 4);
  size_t o_res  = AL((size_t)2 * L_SEQ * DMODEL * 4);
  size_t o_hid  = AL((size_t)2 * L_SEQ * DMODEL * 4);
  size_t o_hn   = AL((size_t)2 * L_SEQ * DMODEL * 2);
  size_t o_xz   = AL((size_t)2 * L_SEQ * E2_ * 2);
  size_t o_xcb  = AL((size_t)2 * L_SEQ * DI_ * 2);
  size_t o_dbc  = AL((size_t)2 * L_SEQ * DBCN * 4);
  size_t o_dbcb = AL((size_t)2 * L_SEQ * KPAD * 2);
  size_t o_dlt  = AL((size_t)2 * L_SEQ * DI_ * 2);
  size_t o_P    = AL((size_t)2 * NCHUNK * DI_ * SSTATE * 4);
  size_t o_Q    = AL((size_t)2 * NCHUNK * DI_ * SSTATE * 4);
  size_t o_hin  = AL((size_t)2 * NCHUNK * DI_ * SSTATE * 4);
  size_t o_yb   = AL((size_t)2 * L_SEQ * DI_ * 2);
  size_t o_hcat = AL((size_t)L_SEQ * DI_ * 2);
  size_t o_proj = AL((size_t)L_SEQ * DMODEL * 2);
  if (ws_size < off) return;

  unsigned short* w_in  = (unsigned short*)(ws + o_win);
  unsigned short* w_xp  = (unsigned short*)(ws + o_wxp);
  unsigned short* w_dtw = (unsigned short*)(ws + o_wdtw);
  unsigned short* w_out = (unsigned short*)(ws + o_wout);
  unsigned short* w_lm  = (unsigned short*)(ws + o_wlm);
  unsigned short* w_emb = (unsigned short*)(ws + o_wemb);
  float* dtb = (float*)(ws + o_dtb);
  float* res = (float*)(ws + o_res);
  float* hid = (float*)(ws + o_hid);
  unsigned short* hn = (unsigned short*)(ws + o_hn);
  unsigned short* xzb = (unsigned short*)(ws + o_xz);
  unsigned short* xcb = (unsigned short*)(ws + o_xcb);
  float* dbc = (float*)(ws + o_dbc);
  unsigned short* dbcb = (unsigned short*)(ws + o_dbcb);
  unsigned short* dltb = (unsigned short*)(ws + o_dlt);
  float* Pg  = (float*)(ws + o_P);
  float* Qg  = (float*)(ws + o_Q);
  float* hing = (float*)(ws + o_hin);
  unsigned short* yb = (unsigned short*)(ws + o_yb);
  unsigned short* hcat = (unsigned short*)(ws + o_hcat);
  unsigned short* projb = (unsigned short*)(ws + o_proj);
  float* logits = (float*)d_out;

  // ---- weight conversions ----
  {
    long n = (long)NLAYER * E2_ * DMODEL;
    cvt2_kernel<<<dim3((n / 4 + 255) / 256, 1, 2), 256, 0, stream>>>(F[0], Bp[0], w_in, n);
    n = (long)NLAYER * DBCN * DI_;
    cvt2_kernel<<<dim3((n / 4 + 255) / 256, 1, 2), 256, 0, stream>>>(F[3], Bp[3], w_xp, n);
    cvtdtw_kernel<<<dim3(((long)NLAYER * DI_ * KPAD + 255) / 256, 1, 2), 256, 0, stream>>>(F[4], Bp[4], w_dtw);
    n = (long)NLAYER * DMODEL * DI_;
    cvt2_kernel<<<dim3((n / 4 + 255) / 256, 1, 2), 256, 0, stream>>>(F[8], Bp[8], w_out, n);
    n = (long)DMODEL * DI_;
    cvt1_kernel<<<dim3((n / 4 + 255) / 256, 1, 1), 256, 0, stream>>>(lm_head, w_lm, n);
    n = (long)VOCAB * DMODEL;
    cvt1_kernel<<<dim3((n / 4 + 255) / 256, 1, 1), 256, 0, stream>>>(embedding, w_emb, n);
    hipMemcpyAsync(dtb, F[5], (size_t)NLAYER * DI_ * 4, hipMemcpyDeviceToDevice, stream);
    hipMemcpyAsync(dtb + NLAYER * DI_, Bp[5], (size_t)NLAYER * DI_ * 4, hipMemcpyDeviceToDevice, stream);
  }

  gather_kernel<<<dim3(L_SEQ * DMODEL / 4 / 256, 1, 2), 256, 0, stream>>>(ids, embedding, res);

  for (int layer = 0; layer < NLAYER; ++layer) {
    addnorm_kernel<<<dim3(L_SEQ, 1, 2), 256, 0, stream>>>(
        res, layer ? hid : nullptr, F[9], Bp[9], layer * DMODEL, hn);
    // xz = hn @ in_proj^T  (M=2048, N=3072, K=768) -> bf16
    gemm_bt<2><<<dim3(E2_ / 128, L_SEQ / 128, 2), 256, 0, stream>>>(
        hn, (long)L_SEQ * DMODEL,
        w_in + (size_t)layer * E2_ * DMODEL, (long)NLAYER * E2_ * DMODEL,
        nullptr, xzb, (long)L_SEQ * E2_, 0, L_SEQ, E2_, DMODEL, nullptr, 0);
    conv_kernel<<<dim3(L_SEQ * DI_ / 256, 1, 2), 256, 0, stream>>>(
        xzb, F[1], Bp[1], F[2], Bp[2], layer, xcb);
    // dbc = x @ x_proj^T (M=2048, N=80, K=1536); fused dual store f32[80] + bf16[64]
    gemm_bt<3><<<dim3(1, L_SEQ / 128, 2), 256, 0, stream>>>(
        xcb, (long)L_SEQ * DI_,
        w_xp + (size_t)layer * DBCN * DI_, (long)NLAYER * DBCN * DI_,
        dbc, dbcb, (long)L_SEQ * DBCN, (long)L_SEQ * KPAD, L_SEQ, DBCN, DI_, nullptr, 0);
    // delta = softplus(dbc[:, :48] @ dt_w^T + dt_b) (M=2048, N=1536, K=64) -> bf16
    gemm_bt<1><<<dim3(DI_ / 128, L_SEQ / 128, 2), 256, 0, stream>>>(
        dbcb, (long)L_SEQ * KPAD,
        w_dtw + (size_t)layer * DI_ * KPAD, (long)NLAYER * DI_ * KPAD,
        nullptr, dltb, (long)L_SEQ * DI_, 0, L_SEQ, DI_, KPAD,
        dtb + layer * DI_, (long)NLAYER * DI_);
    // chunk-parallel scan
    scanA_kernel<<<dim3(DI_ / 16, NCHUNK, 2), 256, 0, stream>>>(
        dltb, xcb, dbc, F[6], Bp[6], layer * DI_ * SSTATE, Pg, Qg);
    scanB_kernel<<<dim3(2 * DI_ * SSTATE / 256, 1, 1), 256, 0, stream>>>(Pg, Qg, hing);
    scanC_kernel<<<dim3(DI_ / 16, NCHUNK, 2), 256, 0, stream>>>(
        dltb, xcb, dbc, xzb, F[6], Bp[6], layer * DI_ * SSTATE,
        F[7], Bp[7], layer * DI_, hing, yb);
    // hid = y @ out_proj^T (M=2048, N=768, K=1536)
    gemm_bt<0><<<dim3(DMODEL / 128, L_SEQ / 128, 2), 256, 0, stream>>>(
        yb, (long)L_SEQ * DI_,
        w_out + (size_t)layer * DMODEL * DI_, (long)NLAYER * DMODEL * DI_,
        hid, nullptr, (long)L_SEQ * DMODEL, 0, L_SEQ, DMODEL, DI_, nullptr, 0);
  }

  finalcat_kernel<<<dim3(L_SEQ, 1, 2), 256, 0, stream>>>(res, hid, F[10], Bp[10], hcat);
  // proj = hcat @ lm_head^T (M=2048, N=768, K=1536) -> bf16
  gemm_bt<2><<<dim3(DMODEL / 128, L_SEQ / 128, 1), 256, 0, stream>>>(
      hcat, 0, w_lm, 0, nullptr, projb, 0, 0, L_SEQ, DMODEL, DI_, nullptr, 0);
  // logits = proj @ embedding^T (M=2048, N=32000, K=768) -> f32 d_out (4-phase 256^2)
  gemm_bt256<<<dim3(VOCAB / 256, L_SEQ / 256, 1), 512, 0, stream>>>(
      projb, w_emb, logits, L_SEQ, VOCAB, DMODEL);
}

// Round 12
// 1009.858 us; speedup vs baseline: 1.0779x; 1.0779x over previous
//
#include <hip/hip_runtime.h>
#include <hip/hip_bf16.h>
#include <stdint.h>

#define L_SEQ 2048
#define DMODEL 768
#define DI_ 1536
#define E2_ 3072
#define NLAYER 2
#define SSTATE 16
#define DBCN 80
#define KPAD 64
#define VOCAB 32000
#define NCHUNK 32
#define TCH 64
#define KSPLIT 8

typedef __bf16 bf16x8 __attribute__((ext_vector_type(8)));
typedef float f32x4 __attribute__((ext_vector_type(4)));

__device__ __forceinline__ unsigned short f2bf(float x) {
  union { float f; uint32_t u; } v; v.f = x;
  uint32_t r = (v.u + 0x7FFFu + ((v.u >> 16) & 1u)) >> 16;
  return (unsigned short)r;
}
__device__ __forceinline__ float bf2f(unsigned short x) {
  union { uint32_t u; float f; } v; v.u = (uint32_t)x << 16; return v.f;
}
__device__ __forceinline__ float siluf_(float x) { return x / (1.f + __expf(-x)); }
__device__ __forceinline__ float softplusf_(float x) {
  return fmaxf(x, 0.f) + log1pf(__expf(-fabsf(x)));
}

// ---------------- weight conversion (vectorized x4) ----------------
__global__ __launch_bounds__(256) void cvt2_kernel(const float* __restrict__ f,
                                                   const float* __restrict__ b,
                                                   unsigned short* __restrict__ dst, long n) {
  long i = ((long)blockIdx.x * 256 + threadIdx.x) * 4;
  if (i >= n) return;
  const float* s = blockIdx.z ? b : f;
  float4 v = *(const float4*)(s + i);
  ushort4 o; o.x = f2bf(v.x); o.y = f2bf(v.y); o.z = f2bf(v.z); o.w = f2bf(v.w);
  *(ushort4*)(dst + (long)blockIdx.z * n + i) = o;
}
__global__ __launch_bounds__(256) void cvt1_kernel(const float* __restrict__ s,
                                                   unsigned short* __restrict__ dst, long n) {
  long i = ((long)blockIdx.x * 256 + threadIdx.x) * 4;
  if (i >= n) return;
  float4 v = *(const float4*)(s + i);
  ushort4 o; o.x = f2bf(v.x); o.y = f2bf(v.y); o.z = f2bf(v.z); o.w = f2bf(v.w);
  *(ushort4*)(dst + i) = o;
}
// dt_w (NLAYER*DI_ rows x 48) -> padded (x64)
__global__ __launch_bounds__(256) void cvtdtw_kernel(const float* __restrict__ f,
                                                     const float* __restrict__ b,
                                                     unsigned short* __restrict__ dst) {
  long n = (long)NLAYER * DI_ * KPAD;
  long i = (long)blockIdx.x * 256 + threadIdx.x;
  if (i >= n) return;
  long r = i >> 6; int c = (int)(i & 63);
  const float* s = blockIdx.z ? b : f;
  dst[(long)blockIdx.z * n + i] = f2bf(c < 48 ? s[r * 48 + c] : 0.f);
}

// ---------------- embedding gather (+flip for dir=1), float4 ----------------
__global__ __launch_bounds__(256) void gather_kernel(const int* __restrict__ ids,
                                                     const float* __restrict__ emb,
                                                     float* __restrict__ res) {
  int idx = blockIdx.x * 256 + threadIdx.x;           // over L*D/4
  int z = blockIdx.z;
  int l = idx / (DMODEL / 4), c = idx % (DMODEL / 4);
  int srcl = z ? (L_SEQ - 1 - l) : l;
  float4 v = *(const float4*)(emb + (size_t)ids[srcl] * DMODEL + c * 4);
  *(float4*)(res + (size_t)z * L_SEQ * DMODEL + (size_t)l * DMODEL + c * 4) = v;
}

// ---------------- residual add + rmsnorm -> bf16 ----------------
__global__ __launch_bounds__(256) void addnorm_kernel(float* __restrict__ res,
                                                      const float* __restrict__ hid,
                                                      const float* __restrict__ wf,
                                                      const float* __restrict__ wb, int woff,
                                                      unsigned short* __restrict__ out) {
  int z = blockIdx.z, l = blockIdx.x, t = threadIdx.x;
  const float* w = (z ? wb : wf) + woff;
  size_t base = ((size_t)z * L_SEQ + l) * DMODEL;
  float v[3]; float ss = 0.f;
  #pragma unroll
  for (int i = 0; i < 3; ++i) {
    int c = t + i * 256;
    float x = res[base + c];
    if (hid) { x += hid[base + c]; res[base + c] = x; }
    v[i] = x; ss += x * x;
  }
  #pragma unroll
  for (int m = 32; m; m >>= 1) ss += __shfl_xor(ss, m);
  __shared__ float red[4];
  if ((t & 63) == 0) red[t >> 6] = ss;
  __syncthreads();
  ss = red[0] + red[1] + red[2] + red[3];
  float inv = rsqrtf(ss * (1.f / DMODEL) + 1e-5f);
  #pragma unroll
  for (int i = 0; i < 3; ++i) {
    int c = t + i * 256;
    out[base + c] = f2bf(v[i] * inv * w[c]);
  }
}

// final rmsnorm(hid+res) -> bf16 into hcat with flip+col-offset for dir=1
__global__ __launch_bounds__(256) void finalcat_kernel(const float* __restrict__ res,
                                                       const float* __restrict__ hid,
                                                       const float* __restrict__ wf,
                                                       const float* __restrict__ wb,
                                                       unsigned short* __restrict__ hcat) {
  int z = blockIdx.z, l = blockIdx.x, t = threadIdx.x;
  const float* w = z ? wb : wf;
  size_t base = ((size_t)z * L_SEQ + l) * DMODEL;
  float v[3]; float ss = 0.f;
  #pragma unroll
  for (int i = 0; i < 3; ++i) {
    int c = t + i * 256;
    float x = res[base + c] + hid[base + c];
    v[i] = x; ss += x * x;
  }
  #pragma unroll
  for (int m = 32; m; m >>= 1) ss += __shfl_xor(ss, m);
  __shared__ float red[4];
  if ((t & 63) == 0) red[t >> 6] = ss;
  __syncthreads();
  ss = red[0] + red[1] + red[2] + red[3];
  float inv = rsqrtf(ss * (1.f / DMODEL) + 1e-5f);
  int outl = z ? (L_SEQ - 1 - l) : l;
  #pragma unroll
  for (int i = 0; i < 3; ++i) {
    int c = t + i * 256;
    hcat[(size_t)outl * DI_ + z * DMODEL + c] = f2bf(v[i] * inv * w[c]);
  }
}

// ---------------- circular depthwise conv K=4 + silu (bf16 in/out) ----------------
__global__ __launch_bounds__(256) void conv_kernel(const unsigned short* __restrict__ xzb,
                                                   const float* __restrict__ cwf,
                                                   const float* __restrict__ cwb,
                                                   const float* __restrict__ cbf,
                                                   const float* __restrict__ cbb, int layer,
                                                   unsigned short* __restrict__ xbf) {
  int z = blockIdx.z;
  int idx = blockIdx.x * 256 + threadIdx.x;           // over L*DI
  int l = idx / DI_, d = idx % DI_;
  const float* cw = (z ? cwb : cwf) + layer * DI_ * 4;
  const float* cb = (z ? cbb : cbf) + layer * DI_;
  const unsigned short* xzp = xzb + (size_t)z * L_SEQ * E2_;
  float acc = cb[d];
  #pragma unroll
  for (int k = 0; k < 4; ++k) {
    int ls = (l + k - 3 + L_SEQ) & (L_SEQ - 1);
    acc += cw[d * 4 + k] * bf2f(xzp[(size_t)ls * E2_ + d]);
  }
  xbf[(size_t)z * L_SEQ * DI_ + idx] = f2bf(siluf_(acc));
}

// ---------------- x_proj split-K reduce: partials -> dbc f32 + dbcb bf16(KPAD) ----
__global__ __launch_bounds__(256) void xpsum_kernel(const float* __restrict__ part,
                                                    float* __restrict__ dbc,
                                                    unsigned short* __restrict__ dbcb) {
  int idx = blockIdx.x * 256 + threadIdx.x;   // over 2*L*80
  int z = idx / (L_SEQ * DBCN);
  int rem = idx % (L_SEQ * DBCN);
  int l = rem / DBCN, c = rem % DBCN;
  float s = 0.f;
  #pragma unroll
  for (int k = 0; k < KSPLIT; ++k)
    s += part[(((size_t)z * KSPLIT + k) * L_SEQ + l) * DBCN + c];
  dbc[((size_t)z * L_SEQ + l) * DBCN + c] = s;
  if (c < KPAD) dbcb[((size_t)z * L_SEQ + l) * KPAD + c] = f2bf(s);
}

// ---------------- chunk-parallel selective scan ----------------
__global__ __launch_bounds__(256) void scanA_kernel(const unsigned short* __restrict__ delta,
                                                    const unsigned short* __restrict__ u,
                                                    const float* __restrict__ dbc,
                                                    const float* __restrict__ Af,
                                                    const float* __restrict__ Ab, int aoff,
                                                    float* __restrict__ Pg,
                                                    float* __restrict__ Qg) {
  const int z = blockIdx.z;
  const int d0 = blockIdx.x * 16;
  const int c = blockIdx.y;
  const int tid = threadIdx.x;
  const int s = tid & 15;
  const int g = tid >> 4;
  const int d = d0 + g;
  __shared__ float sd[16 * 65], su2[16 * 65], sb2[16 * 65];
  const size_t zo = (size_t)z * L_SEQ * DI_;
  const unsigned short* dl = delta + zo;
  const unsigned short* ul = u + zo;
  const float* bc = dbc + (size_t)z * L_SEQ * DBCN;
  const float A = -__expf(((z ? Ab : Af) + aoff)[d * SSTATE + s]);
  const int l0 = c * TCH;
  #pragma unroll
  for (int i = 0; i < 4; ++i) {
    int idx = tid + i * 256;
    int di = idx & 15, li = idx >> 4;
    size_t gl = (size_t)(l0 + li);
    sd[di * 65 + li]  = bf2f(dl[gl * DI_ + d0 + di]);
    su2[di * 65 + li] = bf2f(ul[gl * DI_ + d0 + di]);
    sb2[di * 65 + li] = bc[gl * DBCN + 48 + di];
  }
  __syncthreads();
  float h = 0.f, sda = 0.f;
  #pragma unroll 4
  for (int t = 0; t < TCH; ++t) {
    float dlt = sd[g * 65 + t];
    float uu  = su2[g * 65 + t];
    float bb  = sb2[s * 65 + t];
    float a = __expf(dlt * A);
    h = a * h + dlt * uu * bb;
    sda += dlt;
  }
  size_t o = ((size_t)(z * NCHUNK + c) * DI_ + d) * SSTATE + s;
  Pg[o] = __expf(sda * A);
  Qg[o] = h;
}

__global__ __launch_bounds__(256) void scanB_kernel(const float* __restrict__ Pg,
                                                    const float* __restrict__ Qg,
                                                    float* __restrict__ hin) {
  int idx = blockIdx.x * 256 + threadIdx.x;   // over 2*DI*16
  int z = idx / (DI_ * SSTATE);
  int r = idx % (DI_ * SSTATE);
  float h = 0.f;
  #pragma unroll
  for (int c = 0; c < NCHUNK; ++c) {
    size_t o = (size_t)(z * NCHUNK + c) * DI_ * SSTATE + r;
    hin[o] = h;
    h = Pg[o] * h + Qg[o];
  }
}

__global__ __launch_bounds__(256) void scanC_kernel(const unsigned short* __restrict__ delta,
                                                    const unsigned short* __restrict__ u,
                                                    const float* __restrict__ dbc,
                                                    const unsigned short* __restrict__ xzb,
                                                    const float* __restrict__ Af,
                                                    const float* __restrict__ Ab, int aoff,
                                                    const float* __restrict__ Dpf,
                                                    const float* __restrict__ Dpb, int doff,
                                                    const float* __restrict__ hin,
                                                    unsigned short* __restrict__ yb) {
  const int z = blockIdx.z;
  const int d0 = blockIdx.x * 16;
  const int c = blockIdx.y;
  const int tid = threadIdx.x;
  const int s = tid & 15;
  const int g = tid >> 4;
  const int d = d0 + g;
  __shared__ float sd[16 * 65], su2[16 * 65], sb2[16 * 65], sc2[16 * 65], sy2[16 * 65];
  const size_t zo = (size_t)z * L_SEQ * DI_;
  const unsigned short* dl = delta + zo;
  const unsigned short* ul = u + zo;
  const float* bc = dbc + (size_t)z * L_SEQ * DBCN;
  const float A = -__expf(((z ? Ab : Af) + aoff)[d * SSTATE + s]);
  const int l0 = c * TCH;
  #pragma unroll
  for (int i = 0; i < 4; ++i) {
    int idx = tid + i * 256;
    int di = idx & 15, li = idx >> 4;
    size_t gl = (size_t)(l0 + li);
    sd[di * 65 + li]  = bf2f(dl[gl * DI_ + d0 + di]);
    su2[di * 65 + li] = bf2f(ul[gl * DI_ + d0 + di]);
    sb2[di * 65 + li] = bc[gl * DBCN + 48 + di];
    sc2[di * 65 + li] = bc[gl * DBCN + 64 + di];
  }
  __syncthreads();
  float h = hin[((size_t)(z * NCHUNK + c) * DI_ + d) * SSTATE + s];
  for (int t = 0; t < TCH; t += 2) {
    float dlt0 = sd[g * 65 + t],     uu0 = su2[g * 65 + t];
    float bb0  = sb2[s * 65 + t],    cc0 = sc2[s * 65 + t];
    float dlt1 = sd[g * 65 + t + 1], uu1 = su2[g * 65 + t + 1];
    float bb1  = sb2[s * 65 + t + 1], cc1 = sc2[s * 65 + t + 1];
    float a0 = __expf(dlt0 * A); h = a0 * h + dlt0 * uu0 * bb0; float p0 = h * cc0;
    float a1 = __expf(dlt1 * A); h = a1 * h + dlt1 * uu1 * bb1; float p1 = h * cc1;
    p0 += __shfl_xor(p0, 1); p1 += __shfl_xor(p1, 1);
    p0 += __shfl_xor(p0, 2); p1 += __shfl_xor(p1, 2);
    p0 += __shfl_xor(p0, 4); p1 += __shfl_xor(p1, 4);
    p0 += __shfl_xor(p0, 8); p1 += __shfl_xor(p1, 8);
    if (s == 0) { sy2[g * 65 + t] = p0; sy2[g * 65 + t + 1] = p1; }
  }
  __syncthreads();
  const float* Dp = (z ? Dpb : Dpf) + doff;
  #pragma unroll
  for (int i = 0; i < 4; ++i) {
    int idx = tid + i * 256;
    int di = idx & 15, li = idx >> 4;
    int l = l0 + li;
    float y = sy2[di * 65 + li];
    float uu = su2[di * 65 + li];
    float zz = bf2f(xzb[(size_t)z * L_SEQ * E2_ + (size_t)l * E2_ + DI_ + d0 + di]);
    float v = (y + Dp[d0 + di] * uu) * siluf_(zz);
    yb[zo + (size_t)l * DI_ + d0 + di] = f2bf(v);
  }
}

// ---------------- 128^2 bf16 MFMA GEMM (2-phase dbuf) ----------------
// EPI: 0 = f32, 1 = softplus(v+bias[col]) -> bf16, 2 = bf16,
//      4 = f32 nontemporal (logits: don't evict B panel from L2/L3),
//      5 = split-K f32 partial (grid.x = K-splits, n0 = 0)
template <int EPI>
__global__ __launch_bounds__(256)
void gemm_bt(const unsigned short* __restrict__ Ag, long sAz,
             const unsigned short* __restrict__ Bg, long sBz,
             float* __restrict__ Cf, unsigned short* __restrict__ Cb,
             long sCz, long sCbz,
             int M, int N, int K,
             const float* __restrict__ bias, long sBiasz) {
  __shared__ __align__(16) unsigned short sA[2][128 * 64];
  __shared__ __align__(16) unsigned short sB[2][128 * 64];
  const int tid = threadIdx.x;
  const int lane = tid & 63;
  const int wv = tid >> 6;
  const int z = blockIdx.z;

  int m0, n0, kbeg, nt;
  if constexpr (EPI == 5) {
    m0 = blockIdx.y * 128;
    n0 = 0;
    int klen = K / gridDim.x;
    kbeg = blockIdx.x * klen;
    nt = klen >> 6;
  } else {
    const int nbx = gridDim.x, nby = gridDim.y;
    const int nwg = nbx * nby;
    int hwid = blockIdx.y * nbx + blockIdx.x;
    int q = nwg >> 3, r = nwg & 7;
    int xcd = hwid & 7, slot = hwid >> 3;
    int sbid = (xcd < r ? xcd * (q + 1) : r * (q + 1) + (xcd - r) * q) + slot;
    const int NG = 16;
    int full = nbx / NG;
    int fullBlocks = full * NG * nby;
    int g, na, rem;
    if (sbid < fullBlocks) { g = sbid / (NG * nby); rem = sbid - g * (NG * nby); na = NG; }
    else { g = full; rem = sbid - fullBlocks; na = nbx - full * NG; }
    int ni = rem % na;
    int mi = rem / na;
    n0 = (g * NG + ni) * 128;
    m0 = mi * 128;
    kbeg = 0;
    nt = K >> 6;
  }

  const unsigned short* A = Ag + (size_t)z * sAz;
  const unsigned short* B = Bg + (size_t)z * sBz;
  const int wm = (wv >> 1) * 64;
  const int wn = (wv & 1) * 64;
  const int lr = lane & 15;
  const int lq = lane >> 4;

  f32x4 acc[4][4] = {};

  int prow[4], pcsw[4];
  #pragma unroll
  for (int i = 0; i < 4; ++i) {
    int p = (i * 4 + wv) * 64 + lane;
    int row = p >> 3, sl = p & 7;
    prow[i] = row;
    pcsw[i] = (sl ^ (row & 7)) * 8;
  }

  auto stage = [&](int b, int k0) {
    #pragma unroll
    for (int i = 0; i < 4; ++i) {
      int row = prow[i];
      int ra = m0 + row; if (ra > M - 1) ra = M - 1;
      int rb = n0 + row; if (rb > N - 1) rb = N - 1;
      const unsigned short* ga = A + (size_t)ra * K + k0 + pcsw[i];
      const unsigned short* gb = B + (size_t)rb * K + k0 + pcsw[i];
      __builtin_amdgcn_global_load_lds(
          (const __attribute__((address_space(1))) unsigned int*)ga,
          (__attribute__((address_space(3))) unsigned int*)(sA[b] + (i * 4 + wv) * 512),
          16, 0, 0);
      __builtin_amdgcn_global_load_lds(
          (const __attribute__((address_space(1))) unsigned int*)gb,
          (__attribute__((address_space(3))) unsigned int*)(sB[b] + (i * 4 + wv) * 512),
          16, 0, 0);
    }
  };

  stage(0, kbeg);
  __syncthreads();
  int cur = 0;
  for (int t = 0; t < nt; ++t) {
    if (t + 1 < nt) stage(cur ^ 1, kbeg + ((t + 1) << 6));
    #pragma unroll
    for (int kk = 0; kk < 64; kk += 32) {
      bf16x8 af[4], bfr[4];
      const int ks = (kk >> 3) + lq;
      #pragma unroll
      for (int i = 0; i < 4; ++i) {
        int rra = wm + i * 16 + lr;
        int rrb = wn + i * 16 + lr;
        af[i]  = *(const bf16x8*)(sA[cur] + rra * 64 + ((ks ^ (rra & 7)) << 3));
        bfr[i] = *(const bf16x8*)(sB[cur] + rrb * 64 + ((ks ^ (rrb & 7)) << 3));
      }
      #pragma unroll
      for (int mi2 = 0; mi2 < 4; ++mi2)
        #pragma unroll
        for (int ni2 = 0; ni2 < 4; ++ni2)
          acc[mi2][ni2] = __builtin_amdgcn_mfma_f32_16x16x32_bf16(af[mi2], bfr[ni2], acc[mi2][ni2], 0, 0, 0);
    }
    __syncthreads();
    cur ^= 1;
  }

  const int orow0 = m0 + wm + lq * 4;
  const int ocol0 = n0 + wn + lr;
  #pragma unroll
  for (int mi2 = 0; mi2 < 4; ++mi2) {
    #pragma unroll
    for (int ni2 = 0; ni2 < 4; ++ni2) {
      int col = ocol0 + ni2 * 16;
      if (col >= N) continue;
      #pragma unroll
      for (int j = 0; j < 4; ++j) {
        int row = orow0 + mi2 * 16 + j;
        if (row >= M) continue;
        float v = acc[mi2][ni2][j];
        if constexpr (EPI == 5) {
          float* Cp = Cf + (size_t)(z * gridDim.x + blockIdx.x) * M * N;
          Cp[(size_t)row * N + col] = v;
        } else if constexpr (EPI == 4) {
          __builtin_nontemporal_store(v, Cf + (size_t)z * sCz + (size_t)row * N + col);
        } else if constexpr (EPI == 1) {
          Cb[(size_t)z * sCz + (size_t)row * N + col] =
              f2bf(softplusf_(v + bias[(size_t)z * sBiasz + col]));
        } else if constexpr (EPI == 2) {
          Cb[(size_t)z * sCz + (size_t)row * N + col] = f2bf(v);
        } else {
          Cf[(size_t)z * sCz + (size_t)row * N + col] = v;
        }
      }
    }
  }
}

// ==================== host launcher ====================
extern "C" void kernel_launch(void* const* d_in, const int* in_sizes, int n_in,
                              void* d_out, int out_size, void* d_ws, size_t ws_size,
                              hipStream_t stream) {
  const int* ids = (const int*)d_in[0];
  const float* embedding = (const float*)d_in[1];
  const float* lm_head = (const float*)d_in[2];
  const float* F[11]; const float* Bp[11];
  for (int i = 0; i < 11; ++i) { F[i] = (const float*)d_in[3 + i]; Bp[i] = (const float*)d_in[14 + i]; }

  char* ws = (char*)d_ws;
  size_t off = 0;
  auto AL = [&](size_t bytes) { size_t o = off; off += (bytes + 255) & ~(size_t)255; return o; };
  size_t o_win  = AL((size_t)2 * NLAYER * E2_ * DMODEL * 2);
  size_t o_wxp  = AL((size_t)2 * NLAYER * DBCN * DI_ * 2);
  size_t o_wdtw = AL((size_t)2 * NLAYER * DI_ * KPAD * 2);
  size_t o_wout = AL((size_t)2 * NLAYER * DMODEL * DI_ * 2);
  size_t o_wlm  = AL((size_t)DMODEL * DI_ * 2);
  size_t o_wemb = AL((size_t)VOCAB * DMODEL * 2);
  size_t o_dtb  = AL((size_t)2 * NLAYER * DI_ * 4);
  size_t o_res  = AL((size_t)2 * L_SEQ * DMODEL * 4);
  size_t o_hid  = AL((size_t)2 * L_SEQ * DMODEL * 4);
  size_t o_hn   = AL((size_t)2 * L_SEQ * DMODEL * 2);
  size_t o_xz   = AL((size_t)2 * L_SEQ * E2_ * 2);
  size_t o_xcb  = AL((size_t)2 * L_SEQ * DI_ * 2);
  size_t o_dbc  = AL((size_t)2 * L_SEQ * DBCN * 4);
  size_t o_dbcb = AL((size_t)2 * L_SEQ * KPAD * 2);
  size_t o_xpp  = AL((size_t)2 * KSPLIT * L_SEQ * DBCN * 4);
  size_t o_dlt  = AL((size_t)2 * L_SEQ * DI_ * 2);
  size_t o_P    = AL((size_t)2 * NCHUNK * DI_ * SSTATE * 4);
  size_t o_Q    = AL((size_t)2 * NCHUNK * DI_ * SSTATE * 4);
  size_t o_hin  = AL((size_t)2 * NCHUNK * DI_ * SSTATE * 4);
  size_t o_yb   = AL((size_t)2 * L_SEQ * DI_ * 2);
  size_t o_hcat = AL((size_t)L_SEQ * DI_ * 2);
  size_t o_proj = AL((size_t)L_SEQ * DMODEL * 2);
  if (ws_size < off) return;

  unsigned short* w_in  = (unsigned short*)(ws + o_win);
  unsigned short* w_xp  = (unsigned short*)(ws + o_wxp);
  unsigned short* w_dtw = (unsigned short*)(ws + o_wdtw);
  unsigned short* w_out = (unsigned short*)(ws + o_wout);
  unsigned short* w_lm  = (unsigned short*)(ws + o_wlm);
  unsigned short* w_emb = (unsigned short*)(ws + o_wemb);
  float* dtb = (float*)(ws + o_dtb);
  float* res = (float*)(ws + o_res);
  float* hid = (float*)(ws + o_hid);
  unsigned short* hn = (unsigned short*)(ws + o_hn);
  unsigned short* xzb = (unsigned short*)(ws + o_xz);
  unsigned short* xcb = (unsigned short*)(ws + o_xcb);
  float* dbc = (float*)(ws + o_dbc);
  unsigned short* dbcb = (unsigned short*)(ws + o_dbcb);
  float* xpp = (float*)(ws + o_xpp);
  unsigned short* dltb = (unsigned short*)(ws + o_dlt);
  float* Pg  = (float*)(ws + o_P);
  float* Qg  = (float*)(ws + o_Q);
  float* hing = (float*)(ws + o_hin);
  unsigned short* yb = (unsigned short*)(ws + o_yb);
  unsigned short* hcat = (unsigned short*)(ws + o_hcat);
  unsigned short* projb = (unsigned short*)(ws + o_proj);
  float* logits = (float*)d_out;

  // ---- weight conversions ----
  {
    long n = (long)NLAYER * E2_ * DMODEL;
    cvt2_kernel<<<dim3((n / 4 + 255) / 256, 1, 2), 256, 0, stream>>>(F[0], Bp[0], w_in, n);
    n = (long)NLAYER * DBCN * DI_;
    cvt2_kernel<<<dim3((n / 4 + 255) / 256, 1, 2), 256, 0, stream>>>(F[3], Bp[3], w_xp, n);
    cvtdtw_kernel<<<dim3(((long)NLAYER * DI_ * KPAD + 255) / 256, 1, 2), 256, 0, stream>>>(F[4], Bp[4], w_dtw);
    n = (long)NLAYER * DMODEL * DI_;
    cvt2_kernel<<<dim3((n / 4 + 255) / 256, 1, 2), 256, 0, stream>>>(F[8], Bp[8], w_out, n);
    n = (long)DMODEL * DI_;
    cvt1_kernel<<<dim3((n / 4 + 255) / 256, 1, 1), 256, 0, stream>>>(lm_head, w_lm, n);
    n = (long)VOCAB * DMODEL;
    cvt1_kernel<<<dim3((n / 4 + 255) / 256, 1, 1), 256, 0, stream>>>(embedding, w_emb, n);
    hipMemcpyAsync(dtb, F[5], (size_t)NLAYER * DI_ * 4, hipMemcpyDeviceToDevice, stream);
    hipMemcpyAsync(dtb + NLAYER * DI_, Bp[5], (size_t)NLAYER * DI_ * 4, hipMemcpyDeviceToDevice, stream);
  }

  gather_kernel<<<dim3(L_SEQ * DMODEL / 4 / 256, 1, 2), 256, 0, stream>>>(ids, embedding, res);

  for (int layer = 0; layer < NLAYER; ++layer) {
    addnorm_kernel<<<dim3(L_SEQ, 1, 2), 256, 0, stream>>>(
        res, layer ? hid : nullptr, F[9], Bp[9], layer * DMODEL, hn);
    // xz = hn @ in_proj^T  (M=2048, N=3072, K=768) -> bf16
    gemm_bt<2><<<dim3(E2_ / 128, L_SEQ / 128, 2), 256, 0, stream>>>(
        hn, (long)L_SEQ * DMODEL,
        w_in + (size_t)layer * E2_ * DMODEL, (long)NLAYER * E2_ * DMODEL,
        nullptr, xzb, (long)L_SEQ * E2_, 0, L_SEQ, E2_, DMODEL, nullptr, 0);
    conv_kernel<<<dim3(L_SEQ * DI_ / 256, 1, 2), 256, 0, stream>>>(
        xzb, F[1], Bp[1], F[2], Bp[2], layer, xcb);
    // dbc = x @ x_proj^T (M=2048, N=80, K=1536); split-K 8-way -> partials -> reduce
    gemm_bt<5><<<dim3(KSPLIT, L_SEQ / 128, 2), 256, 0, stream>>>(
        xcb, (long)L_SEQ * DI_,
        w_xp + (size_t)layer * DBCN * DI_, (long)NLAYER * DBCN * DI_,
        xpp, nullptr, 0, 0, L_SEQ, DBCN, DI_, nullptr, 0);
    xpsum_kernel<<<dim3(2 * L_SEQ * DBCN / 256, 1, 1), 256, 0, stream>>>(xpp, dbc, dbcb);
    // delta = softplus(dbc[:, :48] @ dt_w^T + dt_b) (M=2048, N=1536, K=64) -> bf16
    gemm_bt<1><<<dim3(DI_ / 128, L_SEQ / 128, 2), 256, 0, stream>>>(
        dbcb, (long)L_SEQ * KPAD,
        w_dtw + (size_t)layer * DI_ * KPAD, (long)NLAYER * DI_ * KPAD,
        nullptr, dltb, (long)L_SEQ * DI_, 0, L_SEQ, DI_, KPAD,
        dtb + layer * DI_, (long)NLAYER * DI_);
    // chunk-parallel scan
    scanA_kernel<<<dim3(DI_ / 16, NCHUNK, 2), 256, 0, stream>>>(
        dltb, xcb, dbc, F[6], Bp[6], layer * DI_ * SSTATE, Pg, Qg);
    scanB_kernel<<<dim3(2 * DI_ * SSTATE / 256, 1, 1), 256, 0, stream>>>(Pg, Qg, hing);
    scanC_kernel<<<dim3(DI_ / 16, NCHUNK, 2), 256, 0, stream>>>(
        dltb, xcb, dbc, xzb, F[6], Bp[6], layer * DI_ * SSTATE,
        F[7], Bp[7], layer * DI_, hing, yb);
    // hid = y @ out_proj^T (M=2048, N=768, K=1536)
    gemm_bt<0><<<dim3(DMODEL / 128, L_SEQ / 128, 2), 256, 0, stream>>>(
        yb, (long)L_SEQ * DI_,
        w_out + (size_t)layer * DMODEL * DI_, (long)NLAYER * DMODEL * DI_,
        hid, nullptr, (long)L_SEQ * DMODEL, 0, L_SEQ, DMODEL, DI_, nullptr, 0);
  }

  finalcat_kernel<<<dim3(L_SEQ, 1, 2), 256, 0, stream>>>(res, hid, F[10], Bp[10], hcat);
  // proj = hcat @ lm_head^T (M=2048, N=768, K=1536) -> bf16
  gemm_bt<2><<<dim3(DMODEL / 128, L_SEQ / 128, 1), 256, 0, stream>>>(
      hcat, 0, w_lm, 0, nullptr, projb, 0, 0, L_SEQ, DMODEL, DI_, nullptr, 0);
  // logits = proj @ embedding^T (M=2048, N=32000, K=768) -> f32 d_out, nontemporal
  gemm_bt<4><<<dim3(VOCAB / 128, L_SEQ / 128, 1), 256, 0, stream>>>(
      projb, 0, w_emb, 0, logits, nullptr, (long)0, 0, L_SEQ, VOCAB, DMODEL, nullptr, 0);
}

// Round 13
// 986.669 us; speedup vs baseline: 1.1033x; 1.0235x over previous
//
#include <hip/hip_runtime.h>
#include <hip/hip_bf16.h>
#include <stdint.h>

#define L_SEQ 2048
#define DMODEL 768
#define DI_ 1536
#define E2_ 3072
#define NLAYER 2
#define SSTATE 16
#define DBCN 80
#define KPAD 64
#define VOCAB 32000
#define NCHUNK 32
#define TCH 64
#define KSPLIT 8

typedef __bf16 bf16x8 __attribute__((ext_vector_type(8)));
typedef float f32x4 __attribute__((ext_vector_type(4)));

__device__ __forceinline__ unsigned short f2bf(float x) {
  union { float f; uint32_t u; } v; v.f = x;
  uint32_t r = (v.u + 0x7FFFu + ((v.u >> 16) & 1u)) >> 16;
  return (unsigned short)r;
}
__device__ __forceinline__ float bf2f(unsigned short x) {
  union { uint32_t u; float f; } v; v.u = (uint32_t)x << 16; return v.f;
}
__device__ __forceinline__ float siluf_(float x) { return x / (1.f + __expf(-x)); }
__device__ __forceinline__ float softplusf_(float x) {
  return fmaxf(x, 0.f) + log1pf(__expf(-fabsf(x)));
}

// ---------------- weight conversion (vectorized x4) ----------------
__global__ __launch_bounds__(256) void cvt2_kernel(const float* __restrict__ f,
                                                   const float* __restrict__ b,
                                                   unsigned short* __restrict__ dst, long n) {
  long i = ((long)blockIdx.x * 256 + threadIdx.x) * 4;
  if (i >= n) return;
  const float* s = blockIdx.z ? b : f;
  float4 v = *(const float4*)(s + i);
  ushort4 o; o.x = f2bf(v.x); o.y = f2bf(v.y); o.z = f2bf(v.z); o.w = f2bf(v.w);
  *(ushort4*)(dst + (long)blockIdx.z * n + i) = o;
}
__global__ __launch_bounds__(256) void cvt1_kernel(const float* __restrict__ s,
                                                   unsigned short* __restrict__ dst, long n) {
  long i = ((long)blockIdx.x * 256 + threadIdx.x) * 4;
  if (i >= n) return;
  float4 v = *(const float4*)(s + i);
  ushort4 o; o.x = f2bf(v.x); o.y = f2bf(v.y); o.z = f2bf(v.z); o.w = f2bf(v.w);
  *(ushort4*)(dst + i) = o;
}
// dt_w (NLAYER*DI_ rows x 48) -> padded (x64)
__global__ __launch_bounds__(256) void cvtdtw_kernel(const float* __restrict__ f,
                                                     const float* __restrict__ b,
                                                     unsigned short* __restrict__ dst) {
  long n = (long)NLAYER * DI_ * KPAD;
  long i = (long)blockIdx.x * 256 + threadIdx.x;
  if (i >= n) return;
  long r = i >> 6; int c = (int)(i & 63);
  const float* s = blockIdx.z ? b : f;
  dst[(long)blockIdx.z * n + i] = f2bf(c < 48 ? s[r * 48 + c] : 0.f);
}

// ---------------- embedding gather (+flip for dir=1), float4 ----------------
__global__ __launch_bounds__(256) void gather_kernel(const int* __restrict__ ids,
                                                     const float* __restrict__ emb,
                                                     float* __restrict__ res) {
  int idx = blockIdx.x * 256 + threadIdx.x;           // over L*D/4
  int z = blockIdx.z;
  int l = idx / (DMODEL / 4), c = idx % (DMODEL / 4);
  int srcl = z ? (L_SEQ - 1 - l) : l;
  float4 v = *(const float4*)(emb + (size_t)ids[srcl] * DMODEL + c * 4);
  *(float4*)(res + (size_t)z * L_SEQ * DMODEL + (size_t)l * DMODEL + c * 4) = v;
}

// ---------------- residual add + rmsnorm -> bf16 ----------------
__global__ __launch_bounds__(256) void addnorm_kernel(float* __restrict__ res,
                                                      const float* __restrict__ hid,
                                                      const float* __restrict__ wf,
                                                      const float* __restrict__ wb, int woff,
                                                      unsigned short* __restrict__ out) {
  int z = blockIdx.z, l = blockIdx.x, t = threadIdx.x;
  const float* w = (z ? wb : wf) + woff;
  size_t base = ((size_t)z * L_SEQ + l) * DMODEL;
  float v[3]; float ss = 0.f;
  #pragma unroll
  for (int i = 0; i < 3; ++i) {
    int c = t + i * 256;
    float x = res[base + c];
    if (hid) { x += hid[base + c]; res[base + c] = x; }
    v[i] = x; ss += x * x;
  }
  #pragma unroll
  for (int m = 32; m; m >>= 1) ss += __shfl_xor(ss, m);
  __shared__ float red[4];
  if ((t & 63) == 0) red[t >> 6] = ss;
  __syncthreads();
  ss = red[0] + red[1] + red[2] + red[3];
  float inv = rsqrtf(ss * (1.f / DMODEL) + 1e-5f);
  #pragma unroll
  for (int i = 0; i < 3; ++i) {
    int c = t + i * 256;
    out[base + c] = f2bf(v[i] * inv * w[c]);
  }
}

// final rmsnorm(hid+res) -> bf16 into hcat with flip+col-offset for dir=1
__global__ __launch_bounds__(256) void finalcat_kernel(const float* __restrict__ res,
                                                       const float* __restrict__ hid,
                                                       const float* __restrict__ wf,
                                                       const float* __restrict__ wb,
                                                       unsigned short* __restrict__ hcat) {
  int z = blockIdx.z, l = blockIdx.x, t = threadIdx.x;
  const float* w = z ? wb : wf;
  size_t base = ((size_t)z * L_SEQ + l) * DMODEL;
  float v[3]; float ss = 0.f;
  #pragma unroll
  for (int i = 0; i < 3; ++i) {
    int c = t + i * 256;
    float x = res[base + c] + hid[base + c];
    v[i] = x; ss += x * x;
  }
  #pragma unroll
  for (int m = 32; m; m >>= 1) ss += __shfl_xor(ss, m);
  __shared__ float red[4];
  if ((t & 63) == 0) red[t >> 6] = ss;
  __syncthreads();
  ss = red[0] + red[1] + red[2] + red[3];
  float inv = rsqrtf(ss * (1.f / DMODEL) + 1e-5f);
  int outl = z ? (L_SEQ - 1 - l) : l;
  #pragma unroll
  for (int i = 0; i < 3; ++i) {
    int c = t + i * 256;
    hcat[(size_t)outl * DI_ + z * DMODEL + c] = f2bf(v[i] * inv * w[c]);
  }
}

// ---------------- circular depthwise conv K=4 + silu (bf16 in/out) ----------------
__global__ __launch_bounds__(256) void conv_kernel(const unsigned short* __restrict__ xzb,
                                                   const float* __restrict__ cwf,
                                                   const float* __restrict__ cwb,
                                                   const float* __restrict__ cbf,
                                                   const float* __restrict__ cbb, int layer,
                                                   unsigned short* __restrict__ xbf) {
  int z = blockIdx.z;
  int idx = blockIdx.x * 256 + threadIdx.x;           // over L*DI
  int l = idx / DI_, d = idx % DI_;
  const float* cw = (z ? cwb : cwf) + layer * DI_ * 4;
  const float* cb = (z ? cbb : cbf) + layer * DI_;
  const unsigned short* xzp = xzb + (size_t)z * L_SEQ * E2_;
  float acc = cb[d];
  #pragma unroll
  for (int k = 0; k < 4; ++k) {
    int ls = (l + k - 3 + L_SEQ) & (L_SEQ - 1);
    acc += cw[d * 4 + k] * bf2f(xzp[(size_t)ls * E2_ + d]);
  }
  xbf[(size_t)z * L_SEQ * DI_ + idx] = f2bf(siluf_(acc));
}

// ---------------- x_proj split-K reduce: partials -> dbc f32 + dbcb bf16(KPAD) ----
__global__ __launch_bounds__(256) void xpsum_kernel(const float* __restrict__ part,
                                                    float* __restrict__ dbc,
                                                    unsigned short* __restrict__ dbcb) {
  int idx = blockIdx.x * 256 + threadIdx.x;   // over 2*L*80
  int z = idx / (L_SEQ * DBCN);
  int rem = idx % (L_SEQ * DBCN);
  int l = rem / DBCN, c = rem % DBCN;
  float s = 0.f;
  #pragma unroll
  for (int k = 0; k < KSPLIT; ++k)
    s += part[(((size_t)z * KSPLIT + k) * L_SEQ + l) * DBCN + c];
  dbc[((size_t)z * L_SEQ + l) * DBCN + c] = s;
  if (c < KPAD) dbcb[((size_t)z * L_SEQ + l) * KPAD + c] = f2bf(s);
}

// ---------------- chunk-parallel selective scan ----------------
__global__ __launch_bounds__(256) void scanA_kernel(const unsigned short* __restrict__ delta,
                                                    const unsigned short* __restrict__ u,
                                                    const float* __restrict__ dbc,
                                                    const float* __restrict__ Af,
                                                    const float* __restrict__ Ab, int aoff,
                                                    float* __restrict__ Pg,
                                                    float* __restrict__ Qg) {
  const int z = blockIdx.z;
  const int d0 = blockIdx.x * 16;
  const int c = blockIdx.y;
  const int tid = threadIdx.x;
  const int s = tid & 15;
  const int g = tid >> 4;
  const int d = d0 + g;
  __shared__ float sd[16 * 65], su2[16 * 65], sb2[16 * 65];
  const size_t zo = (size_t)z * L_SEQ * DI_;
  const unsigned short* dl = delta + zo;
  const unsigned short* ul = u + zo;
  const float* bc = dbc + (size_t)z * L_SEQ * DBCN;
  const float A = -__expf(((z ? Ab : Af) + aoff)[d * SSTATE + s]);
  const int l0 = c * TCH;
  #pragma unroll
  for (int i = 0; i < 4; ++i) {
    int idx = tid + i * 256;
    int di = idx & 15, li = idx >> 4;
    size_t gl = (size_t)(l0 + li);
    sd[di * 65 + li]  = bf2f(dl[gl * DI_ + d0 + di]);
    su2[di * 65 + li] = bf2f(ul[gl * DI_ + d0 + di]);
    sb2[di * 65 + li] = bc[gl * DBCN + 48 + di];
  }
  __syncthreads();
  float h = 0.f, sda = 0.f;
  #pragma unroll 4
  for (int t = 0; t < TCH; ++t) {
    float dlt = sd[g * 65 + t];
    float uu  = su2[g * 65 + t];
    float bb  = sb2[s * 65 + t];
    float a = __expf(dlt * A);
    h = a * h + dlt * uu * bb;
    sda += dlt;
  }
  size_t o = ((size_t)(z * NCHUNK + c) * DI_ + d) * SSTATE + s;
  Pg[o] = __expf(sda * A);
  Qg[o] = h;
}

__global__ __launch_bounds__(256) void scanB_kernel(const float* __restrict__ Pg,
                                                    const float* __restrict__ Qg,
                                                    float* __restrict__ hin) {
  int idx = blockIdx.x * 256 + threadIdx.x;   // over 2*DI*16
  int z = idx / (DI_ * SSTATE);
  int r = idx % (DI_ * SSTATE);
  float h = 0.f;
  #pragma unroll
  for (int c = 0; c < NCHUNK; ++c) {
    size_t o = (size_t)(z * NCHUNK + c) * DI_ * SSTATE + r;
    hin[o] = h;
    h = Pg[o] * h + Qg[o];
  }
}

__global__ __launch_bounds__(256) void scanC_kernel(const unsigned short* __restrict__ delta,
                                                    const unsigned short* __restrict__ u,
                                                    const float* __restrict__ dbc,
                                                    const unsigned short* __restrict__ xzb,
                                                    const float* __restrict__ Af,
                                                    const float* __restrict__ Ab, int aoff,
                                                    const float* __restrict__ Dpf,
                                                    const float* __restrict__ Dpb, int doff,
                                                    const float* __restrict__ hin,
                                                    unsigned short* __restrict__ yb) {
  const int z = blockIdx.z;
  const int d0 = blockIdx.x * 16;
  const int c = blockIdx.y;
  const int tid = threadIdx.x;
  const int s = tid & 15;
  const int g = tid >> 4;
  const int d = d0 + g;
  __shared__ float sd[16 * 65], su2[16 * 65], sb2[16 * 65], sc2[16 * 65], sy2[16 * 65];
  const size_t zo = (size_t)z * L_SEQ * DI_;
  const unsigned short* dl = delta + zo;
  const unsigned short* ul = u + zo;
  const float* bc = dbc + (size_t)z * L_SEQ * DBCN;
  const float A = -__expf(((z ? Ab : Af) + aoff)[d * SSTATE + s]);
  const int l0 = c * TCH;
  #pragma unroll
  for (int i = 0; i < 4; ++i) {
    int idx = tid + i * 256;
    int di = idx & 15, li = idx >> 4;
    size_t gl = (size_t)(l0 + li);
    sd[di * 65 + li]  = bf2f(dl[gl * DI_ + d0 + di]);
    su2[di * 65 + li] = bf2f(ul[gl * DI_ + d0 + di]);
    sb2[di * 65 + li] = bc[gl * DBCN + 48 + di];
    sc2[di * 65 + li] = bc[gl * DBCN + 64 + di];
  }
  __syncthreads();
  float h = hin[((size_t)(z * NCHUNK + c) * DI_ + d) * SSTATE + s];
  for (int t = 0; t < TCH; t += 2) {
    float dlt0 = sd[g * 65 + t],     uu0 = su2[g * 65 + t];
    float bb0  = sb2[s * 65 + t],    cc0 = sc2[s * 65 + t];
    float dlt1 = sd[g * 65 + t + 1], uu1 = su2[g * 65 + t + 1];
    float bb1  = sb2[s * 65 + t + 1], cc1 = sc2[s * 65 + t + 1];
    float a0 = __expf(dlt0 * A); h = a0 * h + dlt0 * uu0 * bb0; float p0 = h * cc0;
    float a1 = __expf(dlt1 * A); h = a1 * h + dlt1 * uu1 * bb1; float p1 = h * cc1;
    p0 += __shfl_xor(p0, 1); p1 += __shfl_xor(p1, 1);
    p0 += __shfl_xor(p0, 2); p1 += __shfl_xor(p1, 2);
    p0 += __shfl_xor(p0, 4); p1 += __shfl_xor(p1, 4);
    p0 += __shfl_xor(p0, 8); p1 += __shfl_xor(p1, 8);
    if (s == 0) { sy2[g * 65 + t] = p0; sy2[g * 65 + t + 1] = p1; }
  }
  __syncthreads();
  const float* Dp = (z ? Dpb : Dpf) + doff;
  #pragma unroll
  for (int i = 0; i < 4; ++i) {
    int idx = tid + i * 256;
    int di = idx & 15, li = idx >> 4;
    int l = l0 + li;
    float y = sy2[di * 65 + li];
    float uu = su2[di * 65 + li];
    float zz = bf2f(xzb[(size_t)z * L_SEQ * E2_ + (size_t)l * E2_ + DI_ + d0 + di]);
    float v = (y + Dp[d0 + di] * uu) * siluf_(zz);
    yb[zo + (size_t)l * DI_ + d0 + di] = f2bf(v);
  }
}

// ---------------- 128^2 bf16 MFMA GEMM (2-phase dbuf) ----------------
// EPI: 0 = f32, 1 = softplus(v+bias[col]) -> bf16, 2 = bf16,
//      4 = f32 nontemporal (logits: don't evict B panel from L2/L3),
//      5 = split-K f32 partial (grid.x = K-splits, n0 = 0)
template <int EPI>
__global__ __launch_bounds__(256)
void gemm_bt(const unsigned short* __restrict__ Ag, long sAz,
             const unsigned short* __restrict__ Bg, long sBz,
             float* __restrict__ Cf, unsigned short* __restrict__ Cb,
             long sCz, long sCbz,
             int M, int N, int K,
             const float* __restrict__ bias, long sBiasz) {
  __shared__ __align__(16) unsigned short sA[2][128 * 64];
  __shared__ __align__(16) unsigned short sB[2][128 * 64];
  const int tid = threadIdx.x;
  const int lane = tid & 63;
  const int wv = tid >> 6;
  const int z = blockIdx.z;

  int m0, n0, kbeg, nt;
  if constexpr (EPI == 5) {
    m0 = blockIdx.y * 128;
    n0 = 0;
    int klen = K / gridDim.x;
    kbeg = blockIdx.x * klen;
    nt = klen >> 6;
  } else {
    const int nbx = gridDim.x, nby = gridDim.y;
    const int nwg = nbx * nby;
    int hwid = blockIdx.y * nbx + blockIdx.x;
    int q = nwg >> 3, r = nwg & 7;
    int xcd = hwid & 7, slot = hwid >> 3;
    int sbid = (xcd < r ? xcd * (q + 1) : r * (q + 1) + (xcd - r) * q) + slot;
    const int NG = 16;
    int full = nbx / NG;
    int fullBlocks = full * NG * nby;
    int g, na, rem;
    if (sbid < fullBlocks) { g = sbid / (NG * nby); rem = sbid - g * (NG * nby); na = NG; }
    else { g = full; rem = sbid - fullBlocks; na = nbx - full * NG; }
    int ni = rem % na;
    int mi = rem / na;
    n0 = (g * NG + ni) * 128;
    m0 = mi * 128;
    kbeg = 0;
    nt = K >> 6;
  }

  const unsigned short* A = Ag + (size_t)z * sAz;
  const unsigned short* B = Bg + (size_t)z * sBz;
  const int wm = (wv >> 1) * 64;
  const int wn = (wv & 1) * 64;
  const int lr = lane & 15;
  const int lq = lane >> 4;

  f32x4 acc[4][4] = {};

  int prow[4], pcsw[4];
  #pragma unroll
  for (int i = 0; i < 4; ++i) {
    int p = (i * 4 + wv) * 64 + lane;
    int row = p >> 3, sl = p & 7;
    prow[i] = row;
    pcsw[i] = (sl ^ (row & 7)) * 8;
  }

  auto stage = [&](int b, int k0) {
    #pragma unroll
    for (int i = 0; i < 4; ++i) {
      int row = prow[i];
      int ra = m0 + row; if (ra > M - 1) ra = M - 1;
      int rb = n0 + row; if (rb > N - 1) rb = N - 1;
      const unsigned short* ga = A + (size_t)ra * K + k0 + pcsw[i];
      const unsigned short* gb = B + (size_t)rb * K + k0 + pcsw[i];
      __builtin_amdgcn_global_load_lds(
          (const __attribute__((address_space(1))) unsigned int*)ga,
          (__attribute__((address_space(3))) unsigned int*)(sA[b] + (i * 4 + wv) * 512),
          16, 0, 0);
      __builtin_amdgcn_global_load_lds(
          (const __attribute__((address_space(1))) unsigned int*)gb,
          (__attribute__((address_space(3))) unsigned int*)(sB[b] + (i * 4 + wv) * 512),
          16, 0, 0);
    }
  };

  stage(0, kbeg);
  __syncthreads();
  int cur = 0;
  for (int t = 0; t < nt; ++t) {
    if (t + 1 < nt) stage(cur ^ 1, kbeg + ((t + 1) << 6));
    #pragma unroll
    for (int kk = 0; kk < 64; kk += 32) {
      bf16x8 af[4], bfr[4];
      const int ks = (kk >> 3) + lq;
      #pragma unroll
      for (int i = 0; i < 4; ++i) {
        int rra = wm + i * 16 + lr;
        int rrb = wn + i * 16 + lr;
        af[i]  = *(const bf16x8*)(sA[cur] + rra * 64 + ((ks ^ (rra & 7)) << 3));
        bfr[i] = *(const bf16x8*)(sB[cur] + rrb * 64 + ((ks ^ (rrb & 7)) << 3));
      }
      #pragma unroll
      for (int mi2 = 0; mi2 < 4; ++mi2)
        #pragma unroll
        for (int ni2 = 0; ni2 < 4; ++ni2)
          acc[mi2][ni2] = __builtin_amdgcn_mfma_f32_16x16x32_bf16(af[mi2], bfr[ni2], acc[mi2][ni2], 0, 0, 0);
    }
    __syncthreads();
    cur ^= 1;
  }

  const int orow0 = m0 + wm + lq * 4;
  const int ocol0 = n0 + wn + lr;
  #pragma unroll
  for (int mi2 = 0; mi2 < 4; ++mi2) {
    #pragma unroll
    for (int ni2 = 0; ni2 < 4; ++ni2) {
      int col = ocol0 + ni2 * 16;
      if (col >= N) continue;
      #pragma unroll
      for (int j = 0; j < 4; ++j) {
        int row = orow0 + mi2 * 16 + j;
        if (row >= M) continue;
        float v = acc[mi2][ni2][j];
        if constexpr (EPI == 5) {
          float* Cp = Cf + (size_t)(z * gridDim.x + blockIdx.x) * M * N;
          Cp[(size_t)row * N + col] = v;
        } else if constexpr (EPI == 4) {
          __builtin_nontemporal_store(v, Cf + (size_t)z * sCz + (size_t)row * N + col);
        } else if constexpr (EPI == 1) {
          Cb[(size_t)z * sCz + (size_t)row * N + col] =
              f2bf(softplusf_(v + bias[(size_t)z * sBiasz + col]));
        } else if constexpr (EPI == 2) {
          Cb[(size_t)z * sCz + (size_t)row * N + col] = f2bf(v);
        } else {
          Cf[(size_t)z * sCz + (size_t)row * N + col] = v;
        }
      }
    }
  }
}

// ==================== host launcher ====================
extern "C" void kernel_launch(void* const* d_in, const int* in_sizes, int n_in,
                              void* d_out, int out_size, void* d_ws, size_t ws_size,
                              hipStream_t stream) {
  const int* ids = (const int*)d_in[0];
  const float* embedding = (const float*)d_in[1];
  const float* lm_head = (const float*)d_in[2];
  const float* F[11]; const float* Bp[11];
  for (int i = 0; i < 11; ++i) { F[i] = (const float*)d_in[3 + i]; Bp[i] = (const float*)d_in[14 + i]; }

  char* ws = (char*)d_ws;
  size_t off = 0;
  auto AL = [&](size_t bytes) { size_t o = off; off += (bytes + 255) & ~(size_t)255; return o; };
  size_t o_win  = AL((size_t)2 * NLAYER * E2_ * DMODEL * 2);
  size_t o_wxp  = AL((size_t)2 * NLAYER * DBCN * DI_ * 2);
  size_t o_wdtw = AL((size_t)2 * NLAYER * DI_ * KPAD * 2);
  size_t o_wout = AL((size_t)2 * NLAYER * DMODEL * DI_ * 2);
  size_t o_wlm  = AL((size_t)DMODEL * DI_ * 2);
  size_t o_wemb = AL((size_t)VOCAB * DMODEL * 2);
  size_t o_dtb  = AL((size_t)2 * NLAYER * DI_ * 4);
  size_t o_res  = AL((size_t)2 * L_SEQ * DMODEL * 4);
  size_t o_hid  = AL((size_t)2 * L_SEQ * DMODEL * 4);
  size_t o_hn   = AL((size_t)2 * L_SEQ * DMODEL * 2);
  size_t o_xz   = AL((size_t)2 * L_SEQ * E2_ * 2);
  size_t o_xcb  = AL((size_t)2 * L_SEQ * DI_ * 2);
  size_t o_dbc  = AL((size_t)2 * L_SEQ * DBCN * 4);
  size_t o_dbcb = AL((size_t)2 * L_SEQ * KPAD * 2);
  size_t o_xpp  = AL((size_t)2 * KSPLIT * L_SEQ * DBCN * 4);
  size_t o_dlt  = AL((size_t)2 * L_SEQ * DI_ * 2);
  size_t o_P    = AL((size_t)2 * NCHUNK * DI_ * SSTATE * 4);
  size_t o_Q    = AL((size_t)2 * NCHUNK * DI_ * SSTATE * 4);
  size_t o_hin  = AL((size_t)2 * NCHUNK * DI_ * SSTATE * 4);
  size_t o_yb   = AL((size_t)2 * L_SEQ * DI_ * 2);
  size_t o_hcat = AL((size_t)L_SEQ * DI_ * 2);
  size_t o_proj = AL((size_t)L_SEQ * DMODEL * 2);
  if (ws_size < off) return;

  unsigned short* w_in  = (unsigned short*)(ws + o_win);
  unsigned short* w_xp  = (unsigned short*)(ws + o_wxp);
  unsigned short* w_dtw = (unsigned short*)(ws + o_wdtw);
  unsigned short* w_out = (unsigned short*)(ws + o_wout);
  unsigned short* w_lm  = (unsigned short*)(ws + o_wlm);
  unsigned short* w_emb = (unsigned short*)(ws + o_wemb);
  float* dtb = (float*)(ws + o_dtb);
  float* res = (float*)(ws + o_res);
  float* hid = (float*)(ws + o_hid);
  unsigned short* hn = (unsigned short*)(ws + o_hn);
  unsigned short* xzb = (unsigned short*)(ws + o_xz);
  unsigned short* xcb = (unsigned short*)(ws + o_xcb);
  float* dbc = (float*)(ws + o_dbc);
  unsigned short* dbcb = (unsigned short*)(ws + o_dbcb);
  float* xpp = (float*)(ws + o_xpp);
  unsigned short* dltb = (unsigned short*)(ws + o_dlt);
  float* Pg  = (float*)(ws + o_P);
  float* Qg  = (float*)(ws + o_Q);
  float* hing = (float*)(ws + o_hin);
  unsigned short* yb = (unsigned short*)(ws + o_yb);
  unsigned short* hcat = (unsigned short*)(ws + o_hcat);
  unsigned short* projb = (unsigned short*)(ws + o_proj);
  float* logits = (float*)d_out;

  // ---- weight conversions ----
  {
    long n = (long)NLAYER * E2_ * DMODEL;
    cvt2_kernel<<<dim3((n / 4 + 255) / 256, 1, 2), 256, 0, stream>>>(F[0], Bp[0], w_in, n);
    n = (long)NLAYER * DBCN * DI_;
    cvt2_kernel<<<dim3((n / 4 + 255) / 256, 1, 2), 256, 0, stream>>>(F[3], Bp[3], w_xp, n);
    cvtdtw_kernel<<<dim3(((long)NLAYER * DI_ * KPAD + 255) / 256, 1, 2), 256, 0, stream>>>(F[4], Bp[4], w_dtw);
    n = (long)NLAYER * DMODEL * DI_;
    cvt2_kernel<<<dim3((n / 4 + 255) / 256, 1, 2), 256, 0, stream>>>(F[8], Bp[8], w_out, n);
    n = (long)DMODEL * DI_;
    cvt1_kernel<<<dim3((n / 4 + 255) / 256, 1, 1), 256, 0, stream>>>(lm_head, w_lm, n);
    n = (long)VOCAB * DMODEL;
    cvt1_kernel<<<dim3((n / 4 + 255) / 256, 1, 1), 256, 0, stream>>>(embedding, w_emb, n);
    hipMemcpyAsync(dtb, F[5], (size_t)NLAYER * DI_ * 4, hipMemcpyDeviceToDevice, stream);
    hipMemcpyAsync(dtb + NLAYER * DI_, Bp[5], (size_t)NLAYER * DI_ * 4, hipMemcpyDeviceToDevice, stream);
  }

  gather_kernel<<<dim3(L_SEQ * DMODEL / 4 / 256, 1, 2), 256, 0, stream>>>(ids, embedding, res);

  for (int layer = 0; layer < NLAYER; ++layer) {
    addnorm_kernel<<<dim3(L_SEQ, 1, 2), 256, 0, stream>>>(
        res, layer ? hid : nullptr, F[9], Bp[9], layer * DMODEL, hn);
    // xz = hn @ in_proj^T  (M=2048, N=3072, K=768) -> bf16
    gemm_bt<2><<<dim3(E2_ / 128, L_SEQ / 128, 2), 256, 0, stream>>>(
        hn, (long)L_SEQ * DMODEL,
        w_in + (size_t)layer * E2_ * DMODEL, (long)NLAYER * E2_ * DMODEL,
        nullptr, xzb, (long)L_SEQ * E2_, 0, L_SEQ, E2_, DMODEL, nullptr, 0);
    conv_kernel<<<dim3(L_SEQ * DI_ / 256, 1, 2), 256, 0, stream>>>(
        xzb, F[1], Bp[1], F[2], Bp[2], layer, xcb);
    // dbc = x @ x_proj^T (M=2048, N=80, K=1536); split-K 8-way -> partials -> reduce
    gemm_bt<5><<<dim3(KSPLIT, L_SEQ / 128, 2), 256, 0, stream>>>(
        xcb, (long)L_SEQ * DI_,
        w_xp + (size_t)layer * DBCN * DI_, (long)NLAYER * DBCN * DI_,
        xpp, nullptr, 0, 0, L_SEQ, DBCN, DI_, nullptr, 0);
    xpsum_kernel<<<dim3(2 * L_SEQ * DBCN / 256, 1, 1), 256, 0, stream>>>(xpp, dbc, dbcb);
    // delta = softplus(dbc[:, :48] @ dt_w^T + dt_b) (M=2048, N=1536, K=64) -> bf16
    gemm_bt<1><<<dim3(DI_ / 128, L_SEQ / 128, 2), 256, 0, stream>>>(
        dbcb, (long)L_SEQ * KPAD,
        w_dtw + (size_t)layer * DI_ * KPAD, (long)NLAYER * DI_ * KPAD,
        nullptr, dltb, (long)L_SEQ * DI_, 0, L_SEQ, DI_, KPAD,
        dtb + layer * DI_, (long)NLAYER * DI_);
    // chunk-parallel scan
    scanA_kernel<<<dim3(DI_ / 16, NCHUNK, 2), 256, 0, stream>>>(
        dltb, xcb, dbc, F[6], Bp[6], layer * DI_ * SSTATE, Pg, Qg);
    scanB_kernel<<<dim3(2 * DI_ * SSTATE / 256, 1, 1), 256, 0, stream>>>(Pg, Qg, hing);
    scanC_kernel<<<dim3(DI_ / 16, NCHUNK, 2), 256, 0, stream>>>(
        dltb, xcb, dbc, xzb, F[6], Bp[6], layer * DI_ * SSTATE,
        F[7], Bp[7], layer * DI_, hing, yb);
    // hid = y @ out_proj^T (M=2048, N=768, K=1536)
    gemm_bt<0><<<dim3(DMODEL / 128, L_SEQ / 128, 2), 256, 0, stream>>>(
        yb, (long)L_SEQ * DI_,
        w_out + (size_t)layer * DMODEL * DI_, (long)NLAYER * DMODEL * DI_,
        hid, nullptr, (long)L_SEQ * DMODEL, 0, L_SEQ, DMODEL, DI_, nullptr, 0);
  }

  finalcat_kernel<<<dim3(L_SEQ, 1, 2), 256, 0, stream>>>(res, hid, F[10], Bp[10], hcat);
  // proj = hcat @ lm_head^T (M=2048, N=768, K=1536) -> bf16
  gemm_bt<2><<<dim3(DMODEL / 128, L_SEQ / 128, 1), 256, 0, stream>>>(
      hcat, 0, w_lm, 0, nullptr, projb, 0, 0, L_SEQ, DMODEL, DI_, nullptr, 0);
  // logits = proj @ embedding^T (M=2048, N=32000, K=768) -> f32 d_out, nontemporal
  gemm_bt<4><<<dim3(VOCAB / 128, L_SEQ / 128, 1), 256, 0, stream>>>(
      projb, 0, w_emb, 0, logits, nullptr, (long)0, 0, L_SEQ, VOCAB, DMODEL, nullptr, 0);
}